// Round 3
// baseline (103.622 us; speedup 1.0000x reference)
//
#include <hip/hip_runtime.h>

#define B_ 16
#define NPTS 4096            // points per batch (N == M == 4096)

constexpr int JT     = 512;            // target-tile size (LDS: 8 KB of float4)
constexpr int PPT    = 8;              // query points per thread (registers)
constexpr int BLK    = 256;            // threads per block
constexpr int CHUNK  = BLK * PPT;      // 2048 query points per block
constexpr int NCHUNK = NPTS / CHUNK;   // 2
constexpr int NJT    = NPTS / JT;      // 8

// ------------------------------------------------------------------
// main pass: block = (query chunk cx, target tile jt, batch b, dir).
// LDS holds JT prescaled targets {-2x,-2y,-2z,|g|^2}; inner body is a
// 3-fma chain per pair, targets processed in pairs so the two new d^2
// values merge into the running min via v_min3_f32 (3.5 VALU ops/pair).
// PPT=8 queries/thread amortizes the ds_read_b128 to 1 per 512 pairs.
__global__ __launch_bounds__(BLK) void chamfer_pass(
        const float* __restrict__ pred, const float* __restrict__ gt,
        float* __restrict__ partial) {
    const int cx  = blockIdx.x & (NCHUNK - 1);   // query chunk
    const int jt  = blockIdx.x >> 1;             // target tile
    const int b   = blockIdx.y;
    const int dir = blockIdx.z;

    const float* qsrc = dir ? gt   : pred;       // queries
    const float* tsrc = dir ? pred : gt;         // targets

    __shared__ float4 sh[JT];
    {
        const float* tp = tsrc + (b * NPTS + jt * JT) * 3;
        for (int k = threadIdx.x; k < JT; k += BLK) {
            float x = tp[k * 3 + 0];
            float y = tp[k * 3 + 1];
            float z = tp[k * 3 + 2];
            sh[k] = make_float4(-2.0f * x, -2.0f * y, -2.0f * z,
                                fmaf(x, x, fmaf(y, y, z * z)));
        }
    }

    float px[PPT], py[PPT], pz[PPT], mn[PPT];
    const int qbase = b * NPTS + cx * CHUNK + threadIdx.x;
#pragma unroll
    for (int q = 0; q < PPT; q++) {
        int idx = qbase + q * BLK;
        px[q] = qsrc[idx * 3 + 0];
        py[q] = qsrc[idx * 3 + 1];
        pz[q] = qsrc[idx * 3 + 2];
        mn[q] = 1e30f;
    }
    __syncthreads();

#pragma unroll 4
    for (int j = 0; j < JT; j += 2) {
        float4 g0 = sh[j];       // uniform addr -> broadcast ds_read_b128
        float4 g1 = sh[j + 1];
#pragma unroll
        for (int q = 0; q < PPT; q++) {
            float t0 = fmaf(g0.x, px[q], g0.w);
            t0 = fmaf(g0.y, py[q], t0);
            t0 = fmaf(g0.z, pz[q], t0);
            float t1 = fmaf(g1.x, px[q], g1.w);
            t1 = fmaf(g1.y, py[q], t1);
            t1 = fmaf(g1.z, pz[q], t1);
            mn[q] = fminf(mn[q], fminf(t0, t1));   // -> v_min3_f32
        }
    }

    // partial[dir][b][jt][point] = clamped min d^2 over this tile
    float* slot = partial + ((dir * B_ + b) * NJT + jt) * NPTS + cx * CHUNK;
#pragma unroll
    for (int q = 0; q < PPT; q++) {
        float x2 = fmaf(px[q], px[q], fmaf(py[q], py[q], pz[q] * pz[q]));
        slot[q * BLK + threadIdx.x] = fmaxf(mn[q] + x2, 0.0f);
    }
}

// ------------------------------------------------------------------
// reduce1: 512 blocks; block = (dir*B+b, 256-point segment). Min over
// NJT tile-slots, sqrt, block-sum -> sums[512].
__global__ void reduce1_kernel(const float* __restrict__ partial,
                               float* __restrict__ sums) {
    const int slot = blockIdx.x >> 4;    // (dir*B + b) in [0,32)
    const int seg  = blockIdx.x & 15;    // point segment
    const float* p = partial + slot * (NJT * NPTS) + seg * 256 + threadIdx.x;
    float v = p[0];
#pragma unroll
    for (int jt = 1; jt < NJT; jt++)
        v = fminf(v, p[jt * NPTS]);
    float s = sqrtf(v);
    for (int off = 32; off; off >>= 1) s += __shfl_down(s, off);
    __shared__ float ps[4];
    if ((threadIdx.x & 63) == 0) ps[threadIdx.x >> 6] = s;
    __syncthreads();
    if (threadIdx.x == 0)
        sums[blockIdx.x] = ps[0] + ps[1] + ps[2] + ps[3];
}

// ------------------------------------------------------------------
// reduce2: combine 512 partial sums -> loss; write the 3 outputs.
__global__ void reduce2_kernel(const float* __restrict__ sums,
                               float* __restrict__ out) {
    float s = sums[threadIdx.x] + sums[threadIdx.x + 256];
    for (int off = 32; off; off >>= 1) s += __shfl_down(s, off);
    __shared__ float ps[4];
    if ((threadIdx.x & 63) == 0) ps[threadIdx.x >> 6] = s;
    __syncthreads();
    if (threadIdx.x == 0) {
        float loss = (ps[0] + ps[1] + ps[2] + ps[3]) * (1.0f / (float)(B_ * NPTS));
        out[0] = loss;          // WEIGHT * loss, WEIGHT = 1
        out[1] = loss;          // helper_loss
        out[2] = 0.1f * loss;   // helper_cderr = p1 chamfer * xyz_unit
    }
}

// ------------------------------------------------------------------
extern "C" void kernel_launch(void* const* d_in, const int* in_sizes, int n_in,
                              void* d_out, int out_size, void* d_ws, size_t ws_size,
                              hipStream_t stream) {
    const float* pred = (const float*)d_in[0];
    const float* gt   = (const float*)d_in[1];
    float* out = (float*)d_out;

    char* ws = (char*)d_ws;
    float* partial = (float*)ws;                               // 2*B*NJT*NPTS floats = 4 MB
    float* sums    = (float*)(ws + 2 * B_ * NJT * NPTS * sizeof(float));

    chamfer_pass<<<dim3(NCHUNK * NJT, B_, 2), BLK, 0, stream>>>(pred, gt, partial);
    reduce1_kernel<<<dim3(512), 256, 0, stream>>>(partial, sums);
    reduce2_kernel<<<dim3(1), 256, 0, stream>>>(sums, out);
}